// Round 14
// baseline (140.874 us; speedup 1.0000x reference)
//
#include <hip/hip_runtime.h>
#include <hip/hip_bf16.h>
#include <math.h>

typedef __bf16 bf16;
typedef bf16 bf16x2 __attribute__((ext_vector_type(2)));
typedef bf16 bf16x4 __attribute__((ext_vector_type(4)));
typedef bf16 bf16x8 __attribute__((ext_vector_type(8)));
typedef float f32x4 __attribute__((ext_vector_type(4)));
typedef float f32x16 __attribute__((ext_vector_type(16)));
typedef unsigned int u32x2 __attribute__((ext_vector_type(2)));
typedef unsigned int u32x4 __attribute__((ext_vector_type(4)));

#define B_   16
#define LQ_  256
#define LK_  4096
#define E_   64
#define H_   4
#define EK_  16
#define D_   32
#define LAT_ 32

// ws layout (bytes)
#define OFF_QP    0u          // bf16 [16][256][64]              = 512 KB
#define OFF_KP    524288u     // bf16 [16][4096][64]             = 8 MB
#define OFF_MVFB  8912896u    // bf16 [16][128 tile][2 ks][2 nd][64 lane][8] = 8 MB
#define OFF_NDP   17301504u   // f32  [16 b][4 h][256 q][64] = 4.19 MB atomic accumulator
#define WS_NEED   21495808u

#define LOG2E 1.44269504f

#if __has_builtin(__builtin_amdgcn_exp2f)
#define EXP2F(x) __builtin_amdgcn_exp2f(x)
#else
#define EXP2F(x) exp2f(x)
#endif

__device__ inline f32x4 mfma_bf16(bf16x8 a, bf16x8 b, f32x4 c) {
  return __builtin_amdgcn_mfma_f32_16x16x32_bf16(a, b, c, 0, 0, 0);
}
__device__ inline f32x16 mfma_bf16_32(bf16x8 a, bf16x8 b, f32x16 c) {
  return __builtin_amdgcn_mfma_f32_32x32x16_bf16(a, b, c, 0, 0, 0);
}

// in-register lane32-half swap: a' = {a.lo, b.lo->hi}, b' = {a.hi->lo, b.hi}
__device__ inline void pl32swap(unsigned &a, unsigned &b) {
#if __has_builtin(__builtin_amdgcn_permlane32_swap)
  u32x2 r = __builtin_amdgcn_permlane32_swap(a, b, false, false);
  a = r[0]; b = r[1];
#else
  asm volatile("v_permlane32_swap_b32 %0, %1" : "+v"(a), "+v"(b));
#endif
}

// ---------------------------------------------------------------------------
// Kernel 0: prep.  blocks [0,32): q-proj, [32,544): k-proj, [544,800): mvfB,
// [800,816): zero the 4.19MB ndp atomic accumulator (stream-ordered before
// attn's atomics; harness re-poisons ws every iteration so this is mandatory).
// Proj = MFMA GEMM computing (XW)^T via swapped operands -> bf16x4 stores.
// q scaled by 0.25*log2e (folds 1/sqrt(ek) and exp->exp2).
// mvfB emitted as 32x32x16 B-frags: [b][tile][ks2][nd2][lane64][j8],
// lane = (col&31) + 32*((kk>>3)&1), ks = (kk>>4)&1, j = kk&7, nd = col>>5.
// ---------------------------------------------------------------------------
__global__ __launch_bounds__(256) void prep_kernel(
    const float* __restrict__ query, const float* __restrict__ key,
    const float* __restrict__ value, const int* __restrict__ mask,
    const float* __restrict__ Wq, const float* __restrict__ bq,
    const float* __restrict__ Wk, const float* __restrict__ bk,
    bf16* __restrict__ qp, bf16* __restrict__ kp,
    bf16* __restrict__ mvfB, float* __restrict__ ndp)
{
  __shared__ __align__(16) bf16 s_b[16896];  // 33792 B, unioned across roles
  const int bid = blockIdx.x;
  const int tid = threadIdx.x;

  if (bid < 544) {
    // ---- projection role: 128 rows per block ----
    const bool isQ = bid < 32;
    const int row0 = isQ ? bid * 128 : (bid - 32) * 128;
    const float* in   = isQ ? query : key;
    const float* W    = isQ ? Wq : Wk;
    const float* bias = isQ ? bq : bk;
    bf16* outp        = isQ ? qp : kp;
    const float scal  = isQ ? (0.25f * LOG2E) : 1.0f;

    bf16* sIn = s_b;          // [128][72]
    bf16* sWT = s_b + 9216;   // [64][72]  (W^T: [col][k])

#pragma unroll
    for (int p = 0; p < 8; ++p) {
      int f4 = tid + p * 256;            // 2048 float4
      int row = f4 >> 4, e4 = (f4 & 15) * 4;
      float4 v = *(const float4*)(in + (size_t)(row0 + row) * 64 + e4);
      bf16x4 b4;
      b4[0] = (bf16)v.x; b4[1] = (bf16)v.y; b4[2] = (bf16)v.z; b4[3] = (bf16)v.w;
      *(bf16x4*)(sIn + row * 72 + e4) = b4;
    }
#pragma unroll
    for (int p = 0; p < 4; ++p) {
      int f4 = tid + p * 256;            // 1024 float4
      int k = f4 >> 4, c4 = (f4 & 15) * 4;
      float4 v = *(const float4*)(W + k * 64 + c4);
      sWT[(c4 + 0) * 72 + k] = (bf16)v.x;
      sWT[(c4 + 1) * 72 + k] = (bf16)v.y;
      sWT[(c4 + 2) * 72 + k] = (bf16)v.z;
      sWT[(c4 + 3) * 72 + k] = (bf16)v.w;
    }
    __syncthreads();

    const int w = tid >> 6, l = tid & 63, l15 = l & 15, g = l >> 4;
    // D^T tiles: acc[et][rt] -> e = 16*et + 4*g + r, row = 32*w + 16*rt + l15
    f32x4 acc[4][2];
#pragma unroll
    for (int et = 0; et < 4; ++et)
#pragma unroll
      for (int rt = 0; rt < 2; ++rt) acc[et][rt] = f32x4{0.f, 0.f, 0.f, 0.f};

#pragma unroll
    for (int ks = 0; ks < 2; ++ks) {
      bf16x8 X0 = *(bf16x8*)(sIn + (32 * w + l15) * 72 + 32 * ks + 8 * g);
      bf16x8 X1 = *(bf16x8*)(sIn + (32 * w + 16 + l15) * 72 + 32 * ks + 8 * g);
#pragma unroll
      for (int et = 0; et < 4; ++et) {
        bf16x8 Wf = *(bf16x8*)(sWT + (16 * et + l15) * 72 + 32 * ks + 8 * g);
        acc[et][0] = mfma_bf16(Wf, X0, acc[et][0]);
        acc[et][1] = mfma_bf16(Wf, X1, acc[et][1]);
      }
    }
#pragma unroll
    for (int et = 0; et < 4; ++et) {
      f32x4 bv = *(const f32x4*)(bias + 16 * et + 4 * g);  // e-quad bias
#pragma unroll
      for (int rt = 0; rt < 2; ++rt) {
        int row = row0 + 32 * w + 16 * rt + l15;
        bf16x4 o;
#pragma unroll
        for (int r = 0; r < 4; ++r) o[r] = (bf16)((acc[et][rt][r] + bv[r]) * scal);
        *(bf16x4*)(outp + (size_t)row * 64 + 16 * et + 4 * g) = o;
      }
    }
  } else if (bid < 800) {
    // ---- mvfB role: 256-kk chunk -> bf16, 32x32x16-B-frag-ready layout ----
    const int rb = bid - 544;
    const int b = rb >> 4, kk0 = (rb & 15) * 256;
    // s_b as [col 64][kk 256 pad 264]; thread unit = 4 kk x 4 d block
#pragma unroll
    for (int p = 0; p < 2; ++p) {
      int unit = tid + p * 256;          // 512 units: 8 d-groups x 64 kk-groups
      int d4 = (unit & 7) * 4;           // 0..28
      int kk = (unit >> 3) * 4;          // 0..252
      size_t gi = ((size_t)(b * LK_ + kk0 + kk)) * 32 + d4;
      float4 v0 = *(const float4*)(value + gi);
      float4 v1 = *(const float4*)(value + gi + 32);
      float4 v2 = *(const float4*)(value + gi + 64);
      float4 v3 = *(const float4*)(value + gi + 96);
      int4 m0 = *(const int4*)(mask + gi);
      int4 m1 = *(const int4*)(mask + gi + 32);
      int4 m2 = *(const int4*)(mask + gi + 64);
      int4 m3 = *(const int4*)(mask + gi + 96);
      const float* fv[4] = {(const float*)&v0, (const float*)&v1,
                            (const float*)&v2, (const float*)&v3};
      const int*   fm[4] = {(const int*)&m0, (const int*)&m1,
                            (const int*)&m2, (const int*)&m3};
#pragma unroll
      for (int dd = 0; dd < 4; ++dd) {
        bf16x4 a, mk;
#pragma unroll
        for (int i = 0; i < 4; ++i) {
          int mm = fm[i][dd];
          a[i]  = (bf16)(mm ? fv[i][dd] : 0.0f);
          mk[i] = (bf16)(float)mm;
        }
        *(bf16x4*)(s_b + (d4 + dd) * 264 + kk)      = a;   // masked value
        *(bf16x4*)(s_b + (32 + d4 + dd) * 264 + kk) = mk;  // mask
      }
    }
    __syncthreads();
    // writeback: thread owns col = tid>>2, kk range [seg*64, seg*64+64)
    const int col = tid >> 2, seg = tid & 3;
    const int nd = col >> 5, n31 = col & 31;
#pragma unroll
    for (int w2 = 0; w2 < 8; ++w2) {
      int kkg = seg * 64 + w2 * 8;                 // 8-aligned, < 256
      int tile = (kk0 + kkg) >> 5;
      int ks   = (kkg >> 4) & 1;
      int hi2  = (kkg >> 3) & 1;
      int lane = n31 + 32 * hi2;
      uint4 d = *(uint4*)(s_b + col * 264 + kkg);
      *(uint4*)(mvfB + (size_t)((((b * 128 + tile) * 2 + ks) * 2 + nd) * 64 + lane) * 8) = d;
    }
  } else {
    // ---- zero role: clear the 1,048,576-f32 accumulator (16 blocks) ----
    float* z = ndp + (size_t)(bid - 800) * 65536;
#pragma unroll
    for (int p = 0; p < 64; ++p)
      *(f32x4*)(z + (size_t)(tid + p * 256) * 4) = f32x4{0.f, 0.f, 0.f, 0.f};
  }
}

// ---------------------------------------------------------------------------
// Kernel 1: attention — LDS-free main loop (R0 structure, bare v_exp_f32).
// NEW: kc-partials are accumulated with non-returning global_atomic_add_f32
// into a kc-collapsed [b][h][q][64] buffer (4.19MB) instead of 33.5MB of
// plain stores — removes a 67MB HBM round trip through ndp.  8.4M atomics,
// 8-way contention per address, fire-and-forget (not on wave critical path).
// ---------------------------------------------------------------------------
__global__ __launch_bounds__(256, 4) void attn_kernel(
    const bf16* __restrict__ qp, const bf16* __restrict__ kp,
    const bf16* __restrict__ mvfB, float* __restrict__ ndp)
{
  const int bid = blockIdx.x;
  const int kc = bid & 7, qt = (bid >> 3) & 7, b = bid >> 6;
  const int tid = threadIdx.x;
  const int h = tid >> 6, l = tid & 63;
  const int l31 = l & 31, hi = l >> 5;
  const int q0 = qt * 32;
  const int tile0 = kc * 16;   // tiles of 32 kk; 16 per block

  // persistent Q B-frag for 32x32x16: B[k=e][n=q], lane: n=l31, k=8*hi+j
  bf16x8 qB = *(const bf16x8*)(qp + (size_t)((b * LQ_ + q0 + l31) * 64 + h * EK_ + hi * 8));

  f32x16 accN, accD, Z;
#pragma unroll
  for (int i = 0; i < 16; ++i) { accN[i] = 0.f; accD[i] = 0.f; Z[i] = 0.f; }

  const bf16* mvt0 = mvfB + (size_t)(b * 128 + tile0) * 2048;  // 2*2*64*8 per tile
  const bf16* kp_b = kp + (size_t)(b * LK_ + tile0 * 32) * 64 + h * EK_ + hi * 8;

#pragma unroll 2
  for (int t = 0; t < 16; ++t) {
    const bf16* mvt = mvt0 + (size_t)t * 2048;

    // B-frags: (ks,nd) = (0,num),(0,den),(1,num),(1,den); coalesced 16B/lane
    bf16x8 Bn0 = *(const bf16x8*)(mvt + (0 * 64 + l) * 8);
    bf16x8 Bd0 = *(const bf16x8*)(mvt + (1 * 64 + l) * 8);
    bf16x8 Bn1 = *(const bf16x8*)(mvt + (2 * 64 + l) * 8);
    bf16x8 Bd1 = *(const bf16x8*)(mvt + (3 * 64 + l) * 8);

    // kA for 32x32x16: A[m=kk][k=e], lane: m=l31, k=8*hi+j — full wave
    bf16x8 kA = *(const bf16x8*)(kp_b + (size_t)(t * 32 + l31) * 64);

    // transposed scores: one 32x32x16 MFMA, S^T[kk 32][q 32], K=16 exact
    f32x16 S = mfma_bf16_32(kA, qB, Z);

    // exp2 (log2e folded into qp) -> 8 packed bf16 dwords
    unsigned P[8];
#pragma unroll
    for (int i = 0; i < 8; ++i) {
      union { bf16x2 hh; unsigned u; } cv;
      cv.hh[0] = (bf16)EXP2F(S[2 * i + 0]);
      cv.hh[1] = (bf16)EXP2F(S[2 * i + 1]);
      P[i] = cv.u;
    }
    // in-register transpose to 32x32x16 A-frag layout (lane m=l31, k=8*hi+j)
    pl32swap(P[0], P[2]);
    pl32swap(P[1], P[3]);
    pl32swap(P[4], P[6]);
    pl32swap(P[5], P[7]);
    union { u32x4 u; bf16x8 v; } pa0, pa1;
    pa0.u = (u32x4){P[0], P[1], P[2], P[3]};
    pa1.u = (u32x4){P[4], P[5], P[6], P[7]};

    // PV: 4x 32x32x16, acc[q32][col32] for num and den
    accN = mfma_bf16_32(pa0.v, Bn0, accN);
    accD = mfma_bf16_32(pa0.v, Bd0, accD);
    accN = mfma_bf16_32(pa1.v, Bn1, accN);
    accD = mfma_bf16_32(pa1.v, Bd1, accD);
  }

  // epilogue: atomic kc-accumulate.  D-layout: col=l31, q=(r&3)+8*(r>>2)+4*hi
  float* ndp_w = ndp + (((size_t)(b * H_ + h)) * LQ_ + q0) * 64;
#pragma unroll
  for (int r = 0; r < 16; ++r) {
    int q = (r & 3) + 8 * (r >> 2) + 4 * hi;
    atomicAdd(&ndp_w[(size_t)q * 64 + l31],      accN[r]);
    atomicAdd(&ndp_w[(size_t)q * 64 + 32 + l31], accD[r]);
  }
}

// ---------------------------------------------------------------------------
// Kernel 2: read the 4.19MB accumulated num/den (L2/L3-hot — written by attn
// moments earlier), divide, x @ Wo + bo.  grid 512 (b, 8-q) x 512 thr.
// ---------------------------------------------------------------------------
__global__ __launch_bounds__(512) void out_kernel(
    const float* __restrict__ ndp, const float* __restrict__ Wo,
    const float* __restrict__ bo, float* __restrict__ out)
{
  __shared__ __align__(16) float s_xf[8][132];   // x = num/den [q][j=h*32+d]
  __shared__ __align__(16) float s_wo[128][32];  // Wo staged
  const int bid = blockIdx.x;
  const int b = bid >> 5, q0 = (bid & 31) * 8;
  const int tid = threadIdx.x;

  // stage Wo: 4096 f32 / 512 thr = 2 f32x4 each, coalesced
#pragma unroll
  for (int p = 0; p < 2; ++p) {
    int f4 = tid + p * 512;            // 1024 float4
    int row = f4 >> 3, c4 = (f4 & 7) * 4;
    *(f32x4*)(&s_wo[row][c4]) = *(const f32x4*)(Wo + row * 32 + c4);
  }

  // divide -> x.  thread (q = tid>>5, c8 = tid&31), tid < 256
  if (tid < 256) {
    const int q = tid >> 5, c8 = tid & 31;
    const int h = c8 >> 3, dq = (c8 & 7) * 4;
    const float* p = ndp + (((size_t)(b * H_ + h)) * LQ_ + q0 + q) * 64 + dq;
    f32x4 n = *(const f32x4*)(p);
    f32x4 d = *(const f32x4*)(p + 32);
#pragma unroll
    for (int i = 0; i < 4; ++i) s_xf[q][h * 32 + dq + i] = n[i] / d[i];
  }
  __syncthreads();

  // out[q][lat] = bo[lat] + sum_j x[q][j] * Wo[j][lat]
  if (tid < 256) {
    const int q = tid >> 5, lat = tid & 31;
    float acc = bo[lat];
#pragma unroll
    for (int j = 0; j < 128; j += 4) {
      f32x4 xv = *(const f32x4*)(&s_xf[q][j]);
      acc += xv[0] * s_wo[j + 0][lat] + xv[1] * s_wo[j + 1][lat]
           + xv[2] * s_wo[j + 2][lat] + xv[3] * s_wo[j + 3][lat];
    }
    out[(size_t)(b * LQ_ + q0 + q) * LAT_ + lat] = acc;
  }
}

extern "C" void kernel_launch(void* const* d_in, const int* in_sizes, int n_in,
                              void* d_out, int out_size, void* d_ws, size_t ws_size,
                              hipStream_t stream) {
  const float* query = (const float*)d_in[0];
  const float* key   = (const float*)d_in[1];
  const float* value = (const float*)d_in[2];
  const int*   mask  = (const int*)d_in[3];
  const float* Wq    = (const float*)d_in[4];
  const float* bq    = (const float*)d_in[5];
  const float* Wk    = (const float*)d_in[6];
  const float* bk    = (const float*)d_in[7];
  const float* Wo    = (const float*)d_in[8];
  const float* bo    = (const float*)d_in[9];
  float* out = (float*)d_out;
  char* ws = (char*)d_ws;

  if (ws_size < (size_t)WS_NEED) return;  // diagnostic: leaves out == 0

  bf16* qp   = (bf16*)(ws + OFF_QP);
  bf16* kp   = (bf16*)(ws + OFF_KP);
  bf16* mvfB = (bf16*)(ws + OFF_MVFB);
  float* ndp = (float*)(ws + OFF_NDP);

  prep_kernel<<<816, 256, 0, stream>>>(query, key, value, mask, Wq, bq, Wk, bk,
                                       qp, kp, mvfB, ndp);
  attn_kernel<<<1024, 256, 0, stream>>>(qp, kp, mvfB, ndp);
  out_kernel<<<512, 512, 0, stream>>>(ndp, Wo, bo, out);
}

// Round 17
// 127.535 us; speedup vs baseline: 1.1046x; 1.1046x over previous
//
#include <hip/hip_runtime.h>
#include <hip/hip_bf16.h>
#include <math.h>

typedef __bf16 bf16;
typedef bf16 bf16x2 __attribute__((ext_vector_type(2)));
typedef bf16 bf16x4 __attribute__((ext_vector_type(4)));
typedef bf16 bf16x8 __attribute__((ext_vector_type(8)));
typedef float f32x4 __attribute__((ext_vector_type(4)));
typedef float f32x16 __attribute__((ext_vector_type(16)));
typedef unsigned int u32x2 __attribute__((ext_vector_type(2)));
typedef unsigned int u32x4 __attribute__((ext_vector_type(4)));

#define B_   16
#define LQ_  256
#define LK_  4096
#define E_   64
#define H_   4
#define EK_  16
#define D_   32
#define LAT_ 32

// ws layout (bytes)
#define OFF_QP    0u          // bf16 [16][256][64]              = 512 KB
#define OFF_KP    524288u     // bf16 [16][4096][64]             = 8 MB
#define OFF_MVFB  8912896u    // bf16 [16][128 tile][2 ks][2 nd][64 lane][8] = 8 MB
#define OFF_WOT   17301504u   // (unused this version)
#define OFF_NDP   17309696u   // f32  [8 kc][16 b][4 h][256 q][64] = 33.5 MB (num 0..31, den 32..63)
#define WS_NEED   50864128u

#define LOG2E 1.44269504f

#if __has_builtin(__builtin_amdgcn_exp2f)
#define EXP2F(x) __builtin_amdgcn_exp2f(x)
#else
#define EXP2F(x) exp2f(x)
#endif

__device__ inline f32x4 mfma_bf16(bf16x8 a, bf16x8 b, f32x4 c) {
  return __builtin_amdgcn_mfma_f32_16x16x32_bf16(a, b, c, 0, 0, 0);
}
__device__ inline f32x16 mfma_bf16_32(bf16x8 a, bf16x8 b, f32x16 c) {
  return __builtin_amdgcn_mfma_f32_32x32x16_bf16(a, b, c, 0, 0, 0);
}

// in-register lane32-half swap: a' = {a.lo, b.lo->hi}, b' = {a.hi->lo, b.hi}
__device__ inline void pl32swap(unsigned &a, unsigned &b) {
#if __has_builtin(__builtin_amdgcn_permlane32_swap)
  u32x2 r = __builtin_amdgcn_permlane32_swap(a, b, false, false);
  a = r[0]; b = r[1];
#else
  asm volatile("v_permlane32_swap_b32 %0, %1" : "+v"(a), "+v"(b));
#endif
}

// ---------------------------------------------------------------------------
// Kernel 0: prep.  blocks [0,32): q-proj, [32,544): k-proj, [544,800): mvfB.
// Proj = MFMA GEMM computing (XW)^T via swapped operands -> bf16x4 stores.
// q scaled by 0.25*log2e (folds 1/sqrt(ek) and exp->exp2).
// mvfB emitted as 32x32x16 B-frags: [b][tile][ks2][nd2][lane64][j8],
// lane = (col&31) + 32*((kk>>3)&1), ks = (kk>>4)&1, j = kk&7, nd = col>>5.
// ---------------------------------------------------------------------------
__global__ __launch_bounds__(256) void prep_kernel(
    const float* __restrict__ query, const float* __restrict__ key,
    const float* __restrict__ value, const int* __restrict__ mask,
    const float* __restrict__ Wq, const float* __restrict__ bq,
    const float* __restrict__ Wk, const float* __restrict__ bk,
    bf16* __restrict__ qp, bf16* __restrict__ kp,
    bf16* __restrict__ mvfB)
{
  __shared__ __align__(16) bf16 s_b[16896];  // 33792 B, unioned across roles
  const int bid = blockIdx.x;
  const int tid = threadIdx.x;

  if (bid < 544) {
    // ---- projection role: 128 rows per block ----
    const bool isQ = bid < 32;
    const int row0 = isQ ? bid * 128 : (bid - 32) * 128;
    const float* in   = isQ ? query : key;
    const float* W    = isQ ? Wq : Wk;
    const float* bias = isQ ? bq : bk;
    bf16* outp        = isQ ? qp : kp;
    const float scal  = isQ ? (0.25f * LOG2E) : 1.0f;

    bf16* sIn = s_b;          // [128][72]
    bf16* sWT = s_b + 9216;   // [64][72]  (W^T: [col][k])

#pragma unroll
    for (int p = 0; p < 8; ++p) {
      int f4 = tid + p * 256;            // 2048 float4
      int row = f4 >> 4, e4 = (f4 & 15) * 4;
      float4 v = *(const float4*)(in + (size_t)(row0 + row) * 64 + e4);
      bf16x4 b4;
      b4[0] = (bf16)v.x; b4[1] = (bf16)v.y; b4[2] = (bf16)v.z; b4[3] = (bf16)v.w;
      *(bf16x4*)(sIn + row * 72 + e4) = b4;
    }
#pragma unroll
    for (int p = 0; p < 4; ++p) {
      int f4 = tid + p * 256;            // 1024 float4
      int k = f4 >> 4, c4 = (f4 & 15) * 4;
      float4 v = *(const float4*)(W + k * 64 + c4);
      sWT[(c4 + 0) * 72 + k] = (bf16)v.x;
      sWT[(c4 + 1) * 72 + k] = (bf16)v.y;
      sWT[(c4 + 2) * 72 + k] = (bf16)v.z;
      sWT[(c4 + 3) * 72 + k] = (bf16)v.w;
    }
    __syncthreads();

    const int w = tid >> 6, l = tid & 63, l15 = l & 15, g = l >> 4;
    // D^T tiles: acc[et][rt] -> e = 16*et + 4*g + r, row = 32*w + 16*rt + l15
    f32x4 acc[4][2];
#pragma unroll
    for (int et = 0; et < 4; ++et)
#pragma unroll
      for (int rt = 0; rt < 2; ++rt) acc[et][rt] = f32x4{0.f, 0.f, 0.f, 0.f};

#pragma unroll
    for (int ks = 0; ks < 2; ++ks) {
      bf16x8 X0 = *(bf16x8*)(sIn + (32 * w + l15) * 72 + 32 * ks + 8 * g);
      bf16x8 X1 = *(bf16x8*)(sIn + (32 * w + 16 + l15) * 72 + 32 * ks + 8 * g);
#pragma unroll
      for (int et = 0; et < 4; ++et) {
        bf16x8 Wf = *(bf16x8*)(sWT + (16 * et + l15) * 72 + 32 * ks + 8 * g);
        acc[et][0] = mfma_bf16(Wf, X0, acc[et][0]);
        acc[et][1] = mfma_bf16(Wf, X1, acc[et][1]);
      }
    }
#pragma unroll
    for (int et = 0; et < 4; ++et) {
      f32x4 bv = *(const f32x4*)(bias + 16 * et + 4 * g);  // e-quad bias
#pragma unroll
      for (int rt = 0; rt < 2; ++rt) {
        int row = row0 + 32 * w + 16 * rt + l15;
        bf16x4 o;
#pragma unroll
        for (int r = 0; r < 4; ++r) o[r] = (bf16)((acc[et][rt][r] + bv[r]) * scal);
        *(bf16x4*)(outp + (size_t)row * 64 + 16 * et + 4 * g) = o;
      }
    }
  } else {
    // ---- mvfB role: 256-kk chunk -> bf16, 32x32x16-B-frag-ready layout ----
    const int rb = bid - 544;
    const int b = rb >> 4, kk0 = (rb & 15) * 256;
    // s_b as [col 64][kk 256 pad 264]; thread unit = 4 kk x 4 d block
#pragma unroll
    for (int p = 0; p < 2; ++p) {
      int unit = tid + p * 256;          // 512 units: 8 d-groups x 64 kk-groups
      int d4 = (unit & 7) * 4;           // 0..28
      int kk = (unit >> 3) * 4;          // 0..252
      size_t gi = ((size_t)(b * LK_ + kk0 + kk)) * 32 + d4;
      float4 v0 = *(const float4*)(value + gi);
      float4 v1 = *(const float4*)(value + gi + 32);
      float4 v2 = *(const float4*)(value + gi + 64);
      float4 v3 = *(const float4*)(value + gi + 96);
      int4 m0 = *(const int4*)(mask + gi);
      int4 m1 = *(const int4*)(mask + gi + 32);
      int4 m2 = *(const int4*)(mask + gi + 64);
      int4 m3 = *(const int4*)(mask + gi + 96);
      const float* fv[4] = {(const float*)&v0, (const float*)&v1,
                            (const float*)&v2, (const float*)&v3};
      const int*   fm[4] = {(const int*)&m0, (const int*)&m1,
                            (const int*)&m2, (const int*)&m3};
#pragma unroll
      for (int dd = 0; dd < 4; ++dd) {
        bf16x4 a, mk;
#pragma unroll
        for (int i = 0; i < 4; ++i) {
          int mm = fm[i][dd];
          a[i]  = (bf16)(mm ? fv[i][dd] : 0.0f);
          mk[i] = (bf16)(float)mm;
        }
        *(bf16x4*)(s_b + (d4 + dd) * 264 + kk)      = a;   // masked value
        *(bf16x4*)(s_b + (32 + d4 + dd) * 264 + kk) = mk;  // mask
      }
    }
    __syncthreads();
    // writeback: thread owns col = tid>>2, kk range [seg*64, seg*64+64)
    const int col = tid >> 2, seg = tid & 3;
    const int nd = col >> 5, n31 = col & 31;
#pragma unroll
    for (int w2 = 0; w2 < 8; ++w2) {
      int kkg = seg * 64 + w2 * 8;                 // 8-aligned, < 256
      int tile = (kk0 + kkg) >> 5;
      int ks   = (kkg >> 4) & 1;
      int hi2  = (kkg >> 3) & 1;
      int lane = n31 + 32 * hi2;
      uint4 d = *(uint4*)(s_b + col * 264 + kkg);
      *(uint4*)(mvfB + (size_t)((((b * 128 + tile) * 2 + ks) * 2 + nd) * 64 + lane) * 8) = d;
    }
  }
}

// ---------------------------------------------------------------------------
// Kernel 1: attention — LDS-free; bare v_exp_f32 via __builtin_amdgcn_exp2f.
// One 32x32x16 QK^T MFMA (S^T layout), exp2 -> cvt-pack -> 4 permlane32_swap
// in-register repack to the 32x32x16 A-frag layout, 4x 32x32x16 PV MFMAs.
// ---------------------------------------------------------------------------
__global__ __launch_bounds__(256, 4) void attn_kernel(
    const bf16* __restrict__ qp, const bf16* __restrict__ kp,
    const bf16* __restrict__ mvfB, float* __restrict__ ndp)
{
  const int bid = blockIdx.x;
  const int kc = bid & 7, qt = (bid >> 3) & 7, b = bid >> 6;
  const int tid = threadIdx.x;
  const int h = tid >> 6, l = tid & 63;
  const int l31 = l & 31, hi = l >> 5;
  const int q0 = qt * 32;
  const int tile0 = kc * 16;   // tiles of 32 kk; 16 per block

  // persistent Q B-frag for 32x32x16: B[k=e][n=q], lane: n=l31, k=8*hi+j
  bf16x8 qB = *(const bf16x8*)(qp + (size_t)((b * LQ_ + q0 + l31) * 64 + h * EK_ + hi * 8));

  f32x16 accN, accD, Z;
#pragma unroll
  for (int i = 0; i < 16; ++i) { accN[i] = 0.f; accD[i] = 0.f; Z[i] = 0.f; }

  const bf16* mvt0 = mvfB + (size_t)(b * 128 + tile0) * 2048;  // 2*2*64*8 per tile
  const bf16* kp_b = kp + (size_t)(b * LK_ + tile0 * 32) * 64 + h * EK_ + hi * 8;

#pragma unroll 2
  for (int t = 0; t < 16; ++t) {
    const bf16* mvt = mvt0 + (size_t)t * 2048;

    // B-frags: (ks,nd) = (0,num),(0,den),(1,num),(1,den); coalesced 16B/lane
    bf16x8 Bn0 = *(const bf16x8*)(mvt + (0 * 64 + l) * 8);
    bf16x8 Bd0 = *(const bf16x8*)(mvt + (1 * 64 + l) * 8);
    bf16x8 Bn1 = *(const bf16x8*)(mvt + (2 * 64 + l) * 8);
    bf16x8 Bd1 = *(const bf16x8*)(mvt + (3 * 64 + l) * 8);

    // kA for 32x32x16: A[m=kk][k=e], lane: m=l31, k=8*hi+j — full wave
    bf16x8 kA = *(const bf16x8*)(kp_b + (size_t)(t * 32 + l31) * 64);

    // transposed scores: one 32x32x16 MFMA, S^T[kk 32][q 32], K=16 exact
    f32x16 S = mfma_bf16_32(kA, qB, Z);

    // exp2 (log2e folded into qp) -> 8 packed bf16 dwords
    unsigned P[8];
#pragma unroll
    for (int i = 0; i < 8; ++i) {
      union { bf16x2 hh; unsigned u; } cv;
      cv.hh[0] = (bf16)EXP2F(S[2 * i + 0]);
      cv.hh[1] = (bf16)EXP2F(S[2 * i + 1]);
      P[i] = cv.u;
    }
    // in-register transpose to 32x32x16 A-frag layout (lane m=l31, k=8*hi+j)
    pl32swap(P[0], P[2]);
    pl32swap(P[1], P[3]);
    pl32swap(P[4], P[6]);
    pl32swap(P[5], P[7]);
    union { u32x4 u; bf16x8 v; } pa0, pa1;
    pa0.u = (u32x4){P[0], P[1], P[2], P[3]};
    pa1.u = (u32x4){P[4], P[5], P[6], P[7]};

    // PV: 4x 32x32x16, acc[q32][col32] for num and den
    accN = mfma_bf16_32(pa0.v, Bn0, accN);
    accD = mfma_bf16_32(pa0.v, Bd0, accD);
    accN = mfma_bf16_32(pa1.v, Bn1, accN);
    accD = mfma_bf16_32(pa1.v, Bd1, accD);
  }

  // epilogue: 32x32 D-layout: col=l31, row q=(r&3)+8*(r>>2)+4*hi
  float* ndp_w = ndp + ((((size_t)kc * B_ + b) * H_ + h) * LQ_ + q0) * 64;
#pragma unroll
  for (int r = 0; r < 16; ++r) {
    int q = (r & 3) + 8 * (r >> 2) + 4 * hi;
    ndp_w[(size_t)q * 64 + l31]      = accN[r];
    ndp_w[(size_t)q * 64 + 32 + l31] = accD[r];
  }
}

// ---------------------------------------------------------------------------
// Kernel 2: grid 512 (b, 8-q group) x 512 threads — 2 blocks/CU.
// Phases: (1) 512-thr raw num/den kc-reduction into LDS; (2) 256-thr divide
// -> x f32; (3) 256-thr VALU dot against LDS-staged Wo.
// ---------------------------------------------------------------------------
__global__ __launch_bounds__(512) void out_kernel(
    const float* __restrict__ ndp, const float* __restrict__ Wo,
    const float* __restrict__ bo, float* __restrict__ out)
{
  __shared__ __align__(16) float s_nd[8][256];   // raw kc-sums [q][h*64 + d(num 0..31|den 32..63)]
  __shared__ __align__(16) float s_xf[8][132];   // x = num/den [q][j=h*32+d]
  __shared__ __align__(16) float s_wo[128][32];  // Wo staged
  const int bid = blockIdx.x;
  const int b = bid >> 5, q0 = (bid & 31) * 8;
  const int tid = threadIdx.x;

  // stage Wo: 4096 f32 / 512 thr = 2 f32x4 each, coalesced
#pragma unroll
  for (int p = 0; p < 2; ++p) {
    int f4 = tid + p * 512;            // 1024 float4
    int row = f4 >> 3, c4 = (f4 & 7) * 4;
    *(f32x4*)(&s_wo[row][c4]) = *(const f32x4*)(Wo + row * 32 + c4);
  }

  // phase 1: kc-reduce raw sums.  thread -> (q = tid>>6, c16 = tid&63)
  {
    const int q = tid >> 6, c16 = tid & 63;
    const int h = c16 >> 4, dq = (c16 & 15) * 4;   // dq 0..60 spans num+den
    f32x4 s = f32x4{0.f, 0.f, 0.f, 0.f};
#pragma unroll
    for (int kc = 0; kc < 8; ++kc) {
      const float* p = ndp + ((((size_t)kc * B_ + b) * H_ + h) * LQ_ + q0 + q) * 64 + dq;
      s += *(const f32x4*)p;
    }
    *(f32x4*)(&s_nd[q][h * 64 + dq]) = s;
  }
  __syncthreads();

  // phase 2: divide -> x.  thread (q = tid>>5, c8 = tid&31), tid < 256
  if (tid < 256) {
    const int q = tid >> 5, c8 = tid & 31;
    const int h = c8 >> 3, dq = (c8 & 7) * 4;
    f32x4 n = *(const f32x4*)(&s_nd[q][h * 64 + dq]);
    f32x4 d = *(const f32x4*)(&s_nd[q][h * 64 + 32 + dq]);
#pragma unroll
    for (int i = 0; i < 4; ++i) s_xf[q][h * 32 + dq + i] = n[i] / d[i];
  }
  __syncthreads();

  // phase 3: out[q][lat] = bo[lat] + sum_j x[q][j] * Wo[j][lat]
  if (tid < 256) {
    const int q = tid >> 5, lat = tid & 31;
    float acc = bo[lat];
#pragma unroll
    for (int j = 0; j < 128; j += 4) {
      f32x4 xv = *(const f32x4*)(&s_xf[q][j]);
      acc += xv[0] * s_wo[j + 0][lat] + xv[1] * s_wo[j + 1][lat]
           + xv[2] * s_wo[j + 2][lat] + xv[3] * s_wo[j + 3][lat];
    }
    out[(size_t)(b * LQ_ + q0 + q) * LAT_ + lat] = acc;
  }
}

extern "C" void kernel_launch(void* const* d_in, const int* in_sizes, int n_in,
                              void* d_out, int out_size, void* d_ws, size_t ws_size,
                              hipStream_t stream) {
  const float* query = (const float*)d_in[0];
  const float* key   = (const float*)d_in[1];
  const float* value = (const float*)d_in[2];
  const int*   mask  = (const int*)d_in[3];
  const float* Wq    = (const float*)d_in[4];
  const float* bq    = (const float*)d_in[5];
  const float* Wk    = (const float*)d_in[6];
  const float* bk    = (const float*)d_in[7];
  const float* Wo    = (const float*)d_in[8];
  const float* bo    = (const float*)d_in[9];
  float* out = (float*)d_out;
  char* ws = (char*)d_ws;

  if (ws_size < (size_t)WS_NEED) return;  // diagnostic: leaves out == 0

  bf16* qp   = (bf16*)(ws + OFF_QP);
  bf16* kp   = (bf16*)(ws + OFF_KP);
  bf16* mvfB = (bf16*)(ws + OFF_MVFB);
  float* ndp = (float*)(ws + OFF_NDP);

  prep_kernel<<<800, 256, 0, stream>>>(query, key, value, mask, Wq, bq, Wk, bk,
                                       qp, kp, mvfB);
  attn_kernel<<<1024, 256, 0, stream>>>(qp, kp, mvfB, ndp);
  out_kernel<<<512, 512, 0, stream>>>(ndp, Wo, bo, out);
}